// Round 7
// baseline (358.541 us; speedup 1.0000x reference)
//
#include <hip/hip_runtime.h>

#define N_PTS 131072
#define LOG2_T 19
#define TABLE_SIZE (1u << LOG2_T)
#define HASH_MASK (TABLE_SIZE - 1u)

typedef float f32x2 __attribute__((ext_vector_type(2)));
typedef float f32x4 __attribute__((ext_vector_type(4)));
typedef _Float16 h16x2 __attribute__((ext_vector_type(2)));
typedef _Float16 h16x4 __attribute__((ext_vector_type(4)));

#define FSCALE 512.0f
#define INV_FSCALE (1.0f / 512.0f)

// Convert fp32 tables -> fp16 (x512 so all values are fp16-normal; descaled in
// gather). Halves per-combo working set to 2MB (L2-resident) and total table
// footprint to 128MB (L3-resident with headroom). NT loads: fp32 source is
// dead after this, don't let it evict the fp16 copies from L3.
__global__ __launch_bounds__(256) void earth4d_convert(
    const float* __restrict__ t0, const float* __restrict__ t1,
    const float* __restrict__ t2, const float* __restrict__ t3,
    h16x4* __restrict__ dst)
{
    const float* srcs[4] = {t0, t1, t2, t3};
    // 64 combos * 512K entries (f32x2) = 16,777,216 quads (2 entries each).
    // quad q: enc = q>>22 (each enc = 4,194,304 quads), dst order == src order
    // per enc -> dst entry index = combo*TABLE_SIZE + entry.
    unsigned tid = blockIdx.x * 256u + threadIdx.x;    // 2,097,152 threads
    #pragma unroll
    for (int it = 0; it < 8; ++it) {
        unsigned q = tid + (unsigned)it * 2097152u;
        const f32x4* src = reinterpret_cast<const f32x4*>(srcs[q >> 22]);
        f32x4 v = __builtin_nontemporal_load(src + (q & 0x3FFFFFu));
        h16x4 h = { (_Float16)(v.x * FSCALE), (_Float16)(v.y * FSCALE),
                    (_Float16)(v.z * FSCALE), (_Float16)(v.w * FSCALE) };
        dst[q] = h;
    }
}

// Gather. Block = one (enc,level) combo, XCD-pinned (combo%8==xcd); 4 points
// per thread, batched idx -> loads -> FMA. MODE 0: fp16 tables in ws + staging.
// MODE 1: fp32 tables + staging. MODE 2: fp32 tables, direct out stores.
template <int MODE>
__global__ __launch_bounds__(256, 2) void earth4d_gather(
    const float* __restrict__ xyzt,
    const float* __restrict__ tab_xyz,
    const float* __restrict__ tab_xyt,
    const float* __restrict__ tab_yzt,
    const float* __restrict__ tab_xzt,
    const h16x2* __restrict__ tab16,
    float* __restrict__ out,
    f32x2* __restrict__ stage)
{
    unsigned b     = blockIdx.x;               // 0..8191
    unsigned xcd   = b & 7u;
    unsigned i     = b >> 3;                   // 0..1023
    unsigned combo = ((i >> 7) << 3) | xcd;    // 0..63, combo%8==xcd
    unsigned chunk = i & 127u;                 // 0..127
    unsigned e     = combo >> 4;               // encoding 0..3
    unsigned l     = combo & 15u;              // level 0..15

    const float* tab;
    switch (e) {
      case 0:  tab = tab_xyz; break;
      case 1:  tab = tab_xyt; break;
      case 2:  tab = tab_yzt; break;
      default: tab = tab_xzt; break;
    }
    const f32x2* tl32 = reinterpret_cast<const f32x2*>(tab) + (size_t)l * TABLE_SIZE;
    const h16x2* tl16 = tab16 + (size_t)combo * TABLE_SIZE;

    unsigned resu = 32u << l;                  // 32 * 2^l, exact
    float res = (float)resu;

    unsigned nbase = (chunk << 10) | threadIdx.x;   // + k*256, k=0..3

    float w0[4], w1[4], w2[4];
    unsigned idx[4][8];

    #pragma unroll
    for (int k = 0; k < 4; ++k) {
        unsigned n = nbase + (unsigned)k * 256u;
        float4 p = reinterpret_cast<const float4*>(xyzt)[n];
        float c0, c1, c2;
        switch (e) {
          case 0:  c0 = p.x; c1 = p.y; c2 = p.z; break;  // xyz
          case 1:  c0 = p.x; c1 = p.y; c2 = p.w; break;  // xyt
          case 2:  c0 = p.y; c1 = p.z; c2 = p.w; break;  // yzt
          default: c0 = p.x; c1 = p.z; c2 = p.w; break;  // xzt
        }
        float p0 = c0 * res, p1 = c1 * res, p2 = c2 * res;   // exact (res=2^k)
        float f0 = floorf(p0), f1 = floorf(p1), f2 = floorf(p2);
        w0[k] = p0 - f0; w1[k] = p1 - f1; w2[k] = p2 - f2;
        int b0 = (int)f0, b1 = (int)f1, b2 = (int)f2;

        if (l < 2u) {
            // dense: (res+1)^3 <= 2^19 only for res in {32, 64}
            int s = (int)resu + 1;
            #pragma unroll
            for (int c = 0; c < 8; ++c) {
                int i0 = b0 + ((c >> 2) & 1);
                int i1 = b1 + ((c >> 1) & 1);
                int i2 = b2 + (c & 1);
                idx[k][c] = (unsigned)(i0 + i1 * s + i2 * s * s);
            }
        } else {
            #pragma unroll
            for (int c = 0; c < 8; ++c) {
                unsigned i0 = (unsigned)(b0 + ((c >> 2) & 1));
                unsigned i1 = (unsigned)(b1 + ((c >> 1) & 1));
                unsigned i2 = (unsigned)(b2 + (c & 1));
                idx[k][c] = (i0 * 1u ^ i1 * 2654435761u ^ i2 * 805459861u) & HASH_MASK;
            }
        }
    }

    float r0[4], r1[4];
    if (MODE == 0) {
        h16x2 v[4][8];
        #pragma unroll
        for (int k = 0; k < 4; ++k)
            #pragma unroll
            for (int c = 0; c < 8; ++c)
                v[k][c] = tl16[idx[k][c]];
        #pragma unroll
        for (int k = 0; k < 4; ++k) {
            float a0 = 0.f, a1 = 0.f;
            #pragma unroll
            for (int c = 0; c < 8; ++c) {
                float wt = ((c & 4) ? w0[k] : 1.f - w0[k])
                         * ((c & 2) ? w1[k] : 1.f - w1[k])
                         * ((c & 1) ? w2[k] : 1.f - w2[k]);
                a0 = fmaf((float)v[k][c].x, wt, a0);
                a1 = fmaf((float)v[k][c].y, wt, a1);
            }
            r0[k] = a0 * INV_FSCALE;
            r1[k] = a1 * INV_FSCALE;
        }
    } else {
        f32x2 v[4][8];
        #pragma unroll
        for (int k = 0; k < 4; ++k)
            #pragma unroll
            for (int c = 0; c < 8; ++c)
                v[k][c] = tl32[idx[k][c]];
        #pragma unroll
        for (int k = 0; k < 4; ++k) {
            float a0 = 0.f, a1 = 0.f;
            #pragma unroll
            for (int c = 0; c < 8; ++c) {
                float wt = ((c & 4) ? w0[k] : 1.f - w0[k])
                         * ((c & 2) ? w1[k] : 1.f - w1[k])
                         * ((c & 1) ? w2[k] : 1.f - w2[k]);
                a0 = fmaf(v[k][c].x, wt, a0);
                a1 = fmaf(v[k][c].y, wt, a1);
            }
            r0[k] = a0;
            r1[k] = a1;
        }
    }

    #pragma unroll
    for (int k = 0; k < 4; ++k) {
        unsigned n = nbase + (unsigned)k * 256u;
        f32x2 r = { r0[k], r1[k] };
        if (MODE != 2) {
            // combo-major: consecutive lanes -> consecutive 8B, full-line NT
            __builtin_nontemporal_store(r, stage + (size_t)combo * N_PTS + n);
        } else {
            __builtin_nontemporal_store(
                r, reinterpret_cast<f32x2*>(out + (size_t)n * 128u + combo * 2u));
        }
    }
}

// Transpose stage[combo][n] -> out[n][128]. 64-point tiles via LDS.
__global__ __launch_bounds__(256) void earth4d_transpose(
    const f32x2* __restrict__ ws, float* __restrict__ out)
{
    __shared__ f32x2 lds[64][65];   // pad: stride 65*8B -> 2-way bank alias (free)
    unsigned n0 = blockIdx.x * 64u;
    unsigned t = threadIdx.x;

    #pragma unroll
    for (int it = 0; it < 16; ++it) {
        unsigned i = (unsigned)it * 256u + t;     // 0..4095
        unsigned c = i >> 6;                      // combo 0..63
        unsigned p = i & 63u;                     // point-in-tile
        lds[p][c] = __builtin_nontemporal_load(ws + (size_t)c * N_PTS + n0 + p);
    }
    __syncthreads();

    #pragma unroll
    for (int it = 0; it < 8; ++it) {
        unsigned i = (unsigned)it * 256u + t;     // 0..2047
        unsigned p = i >> 5;                      // point-in-tile 0..63
        unsigned q = i & 31u;                     // float4 index 0..31
        f32x2 a = lds[p][2u * q];
        f32x2 b = lds[p][2u * q + 1u];
        f32x4 v = { a.x, a.y, b.x, b.y };
        __builtin_nontemporal_store(
            v, reinterpret_cast<f32x4*>(out + (size_t)(n0 + p) * 128u) + q);
    }
}

extern "C" void kernel_launch(void* const* d_in, const int* in_sizes, int n_in,
                              void* d_out, int out_size, void* d_ws, size_t ws_size,
                              hipStream_t stream) {
    const float* xyzt    = (const float*)d_in[0];
    const float* tab_xyz = (const float*)d_in[1];
    const float* tab_xyt = (const float*)d_in[2];
    const float* tab_yzt = (const float*)d_in[3];
    const float* tab_xzt = (const float*)d_in[4];
    float* out = (float*)d_out;

    const size_t TAB16 = (size_t)64 * TABLE_SIZE * sizeof(h16x2);  // 128 MiB
    const size_t STAGE = (size_t)64 * N_PTS * sizeof(f32x2);       //  64 MiB
    dim3 block(256u), grid1(8192u);

    if (d_ws && ws_size >= TAB16 + STAGE) {
        h16x2* tab16 = (h16x2*)d_ws;
        f32x2* stage = (f32x2*)((char*)d_ws + TAB16);
        earth4d_convert<<<dim3(8192u), block, 0, stream>>>(
            tab_xyz, tab_xyt, tab_yzt, tab_xzt, (h16x4*)tab16);
        earth4d_gather<0><<<grid1, block, 0, stream>>>(
            xyzt, tab_xyz, tab_xyt, tab_yzt, tab_xzt, tab16, out, stage);
        earth4d_transpose<<<dim3(N_PTS / 64u), block, 0, stream>>>(stage, out);
    } else if (d_ws && ws_size >= STAGE) {
        f32x2* stage = (f32x2*)d_ws;
        earth4d_gather<1><<<grid1, block, 0, stream>>>(
            xyzt, tab_xyz, tab_xyt, tab_yzt, tab_xzt, (const h16x2*)nullptr, out, stage);
        earth4d_transpose<<<dim3(N_PTS / 64u), block, 0, stream>>>(stage, out);
    } else {
        earth4d_gather<2><<<grid1, block, 0, stream>>>(
            xyzt, tab_xyz, tab_xyt, tab_yzt, tab_xzt, (const h16x2*)nullptr, out, (f32x2*)nullptr);
    }
}